// Round 1
// baseline (258.280 us; speedup 1.0000x reference)
//
#include <hip/hip_runtime.h>
#include <cstdint>
#include <cstddef>

typedef unsigned short u16;
typedef __bf16 bf16x8 __attribute__((ext_vector_type(8)));
typedef float f32x4 __attribute__((ext_vector_type(4)));
typedef float f32x16 __attribute__((ext_vector_type(16)));

typedef __attribute__((address_space(1))) void gvoid;
typedef __attribute__((address_space(3))) void lvoid;

__device__ __forceinline__ void g2l16(const void* g, void* l) {
    __builtin_amdgcn_global_load_lds((gvoid*)g, (lvoid*)l, 16, 0, 0);
}

__device__ __forceinline__ u16 f2bf(float f) {
    union { float f; uint32_t u; } v;
    v.f = f;
    uint32_t r = (v.u + 0x7FFFu + ((v.u >> 16) & 1u)) >> 16;
    return (u16)r;
}

// ---------------- fp32 -> bf16 conversion of x, Wqk, Wv, Wo into ws ----------------
__global__ __launch_bounds__(256)
void cvt_kernel(const float* __restrict__ x, const float* __restrict__ wqk,
                const float* __restrict__ wv, const float* __restrict__ wo,
                u16* __restrict__ out) {
    int i = (blockIdx.x * 256 + threadIdx.x) * 4;
    const float* src;
    int off;
    if (i < 4194304)      { src = x;   off = 0; }
    else if (i < 5242880) { src = wqk; off = 4194304; }
    else if (i < 6291456) { src = wv;  off = 5242880; }
    else                  { src = wo;  off = 6291456; }
    float4 v = *(const float4*)(src + (i - off));
    ushort4 o;
    o.x = f2bf(v.x); o.y = f2bf(v.y); o.z = f2bf(v.z); o.w = f2bf(v.w);
    *(ushort4*)(out + i) = o;
}

// ---------------- bf16 GEMM: out[m][n] = sum_k A[m][k]*Bw[n][k] + bias[n] ----------------
// BM=128, BN=64, BK=32, 256 threads (4 waves, 2x2), per-wave 64x32 via 16x16x32 mfma.
// MODE 0: bf16 out [4096][1024];  MODE 1: bf16 transposed v^T [bh=8][d=256][t=2048];  MODE 2: f32 out.
template <int MODE>
__global__ __launch_bounds__(256)
void gemm_kernel(const u16* __restrict__ A, const u16* __restrict__ Bw,
                 const float* __restrict__ bias, void* __restrict__ outp) {
    __shared__ __align__(16) u16 As[128 * 32];
    __shared__ __align__(16) u16 Bs[64 * 32];
    const int bid = blockIdx.x;
    const int m0 = (bid >> 4) * 128;
    const int n0 = (bid & 15) * 64;
    const int t = threadIdx.x;
    const int lane = t & 63;
    const int wid = t >> 6;
    const int wr = wid >> 1, wc = wid & 1;
    const int l15 = lane & 15, l4 = lane >> 4;

    f32x4 acc[4][2] = {};

    for (int kt = 0; kt < 32; ++kt) {
        const int kbase = kt * 32;
#pragma unroll
        for (int c = 0; c < 2; ++c) {
            const int p = c * 4096 + t * 16;          // byte pos in As
            const int row = p >> 6;
            const int koff = (p & 63) >> 1;           // elems
            g2l16(A + (size_t)(m0 + row) * 1024 + kbase + koff, (char*)As + p);
        }
        {
            const int p = t * 16;
            const int row = p >> 6;
            const int koff = (p & 63) >> 1;
            g2l16(Bw + (size_t)(n0 + row) * 1024 + kbase + koff, (char*)Bs + p);
        }
        __syncthreads();
        bf16x8 af[4], bfr[2];
#pragma unroll
        for (int mi = 0; mi < 4; ++mi)
            af[mi] = *(const bf16x8*)((const char*)As + (wr * 64 + mi * 16 + l15) * 64 + l4 * 16);
#pragma unroll
        for (int ni = 0; ni < 2; ++ni)
            bfr[ni] = *(const bf16x8*)((const char*)Bs + (wc * 32 + ni * 16 + l15) * 64 + l4 * 16);
#pragma unroll
        for (int mi = 0; mi < 4; ++mi)
#pragma unroll
            for (int ni = 0; ni < 2; ++ni)
                acc[mi][ni] = __builtin_amdgcn_mfma_f32_16x16x32_bf16(af[mi], bfr[ni], acc[mi][ni], 0, 0, 0);
        __syncthreads();
    }

    const int mbase = m0 + wr * 64 + l4 * 4;
    const int nbase = n0 + wc * 32 + l15;
#pragma unroll
    for (int ni = 0; ni < 2; ++ni) {
        const int n = nbase + ni * 16;
        const float bv = bias[n];
#pragma unroll
        for (int mi = 0; mi < 4; ++mi) {
            const int mrow = mbase + mi * 16;
            if (MODE == 1) {
                const int bq = mrow >> 11, tq = mrow & 2047;
                const int hh = n >> 8, dd = n & 255;
                ushort4 w;
                w.x = f2bf(acc[mi][ni][0] + bv);
                w.y = f2bf(acc[mi][ni][1] + bv);
                w.z = f2bf(acc[mi][ni][2] + bv);
                w.w = f2bf(acc[mi][ni][3] + bv);
                *(ushort4*)((u16*)outp + (size_t)((bq * 4 + hh) * 256 + dd) * 2048 + tq) = w;
            } else if (MODE == 0) {
#pragma unroll
                for (int r = 0; r < 4; ++r)
                    ((u16*)outp)[(size_t)(mrow + r) * 1024 + n] = f2bf(acc[mi][ni][r] + bv);
            } else {
#pragma unroll
                for (int r = 0; r < 4; ++r)
                    ((float*)outp)[(size_t)(mrow + r) * 1024 + n] = acc[mi][ni][r] + bv;
            }
        }
    }
}

// ---------------- spiral flash attention ----------------
// 1 wave per block, 32 query rows per wave, 32x32x16 mfma, swapped operands:
// S^T = mfma(K, Q)  (lane's col = its query), O^T = mfma(V^T, P^T).
__global__ __launch_bounds__(64)
void attn_kernel(const u16* __restrict__ qk, const u16* __restrict__ vt, u16* __restrict__ attnb) {
    __shared__ __align__(16) unsigned char Ks[16384];  // K tile [32 keys][256 d] bf16, swizzled ^(((p>>9)&7)<<4)
    __shared__ __align__(16) unsigned char Vs[16384];  // V^T tile [256 d][32 keys] bf16, swizzled ^(((p>>7)&3)<<4)
    __shared__ __align__(16) unsigned char Ps[2048];   // P [32 q][32 keys] bf16, swizzled ^(((q>>1)&3)<<4)

    const int bid = blockIdx.x;
    const int bh = bid & 7;
    const int qt = 63 - (bid >> 3);       // largest tiles dispatched first
    const int b = bh >> 2, h = bh & 3;
    const int s = (h == 0) ? 1 : ((h == 1) ? 3 : ((h == 2) ? 7 : 13));
    const float rs = 1.0f / (float)s;
    const int l = threadIdx.x;
    const int l31 = l & 31, h5 = l >> 5;
    const int q0 = qt * 32;
    const int q = q0 + l31;               // this lane's query row
    const float c2 = 0.09016844f;         // (1/16) * log2(e)

    // Q fragments: B-operand of S^T mfma: lane holds Q[q][dc*16 + h5*8 + j]
    bf16x8 qf[16];
    {
        const u16* qb = qk + (size_t)(b * 2048 + q) * 1024 + h * 256 + h5 * 8;
#pragma unroll
        for (int dc = 0; dc < 16; ++dc)
            qf[dc] = *(const bf16x8*)(qb + dc * 16);
    }

    f32x16 o[8] = {};
    float mrun = -3.0e38f, lrun = 0.0f;

    const int nkt = qt + 1;
    for (int kt = 0; kt < nkt; ++kt) {
        const int key0 = kt * 32;
        // drain our ds_reads before TA overwrites the LDS tiles
        asm volatile("s_waitcnt lgkmcnt(0)" ::: "memory");
        // stage K tile (pre-swizzled global source, linear LDS dest)
#pragma unroll
        for (int i = 0; i < 16; ++i) {
            const int p = i * 1024 + l * 16;
            const int qb = p ^ (((p >> 9) & 7) << 4);     // involution
            g2l16(qk + (size_t)(b * 2048 + key0 + (qb >> 9)) * 1024 + h * 256 + ((qb & 511) >> 1),
                  Ks + p);
        }
        // stage V^T tile
#pragma unroll
        for (int i = 0; i < 16; ++i) {
            const int p = i * 1024 + l * 16;
            const int qb = p ^ (((p >> 7) & 3) << 4);     // involution
            g2l16(vt + (size_t)(bh * 256 + (qb >> 6)) * 2048 + key0 + ((qb & 63) >> 1),
                  Vs + p);
        }
        asm volatile("s_waitcnt vmcnt(0)" ::: "memory");
        __builtin_amdgcn_sched_barrier(0);

        // S^T = K * Q^T : lane holds col = its query, rows = keys kmap(r,h5)
        f32x16 sacc = {};
#pragma unroll
        for (int dc = 0; dc < 16; ++dc) {
            const int kb = l31 * 512 + dc * 32 + h5 * 16;
            const bf16x8 kf = *(const bf16x8*)(Ks + (kb ^ ((l31 & 7) << 4)));
            sacc = __builtin_amdgcn_mfma_f32_32x32x16_bf16(kf, qf[dc], sacc, 0, 0, 0);
        }

        // mask + online softmax (all state lane-local for query q)
        const int ebase = (key0 - q + 3072) & 2047;
        float sv[16];
        float tmax = -3.0e38f;
#pragma unroll
        for (int r = 0; r < 16; ++r) {
            const int km = (r & 3) + 8 * (r >> 2) + 4 * h5;   // key row within tile
            int e = ebase + km;
            if (e >= 2048) e -= 2048;
            const int md = e - s * (int)((float)e * rs);
            const bool v = ((key0 + km) <= q) && (md == 0);
            sv[r] = v ? sacc[r] : -3.0e38f;
            tmax = fmaxf(tmax, sv[r]);
        }
        tmax = fmaxf(tmax, __shfl_xor(tmax, 32, 64));
        const float mnew = fmaxf(mrun, tmax);
        const float fsc = __builtin_amdgcn_exp2f((mrun - mnew) * c2);
        mrun = mnew;
        float psum = 0.0f;
#pragma unroll
        for (int r = 0; r < 16; ++r) {
            const float p = (sv[r] > -1.0e37f) ? __builtin_amdgcn_exp2f((sv[r] - mnew) * c2) : 0.0f;
            sv[r] = p;
            psum += p;
        }
        lrun = lrun * fsc + psum;
#pragma unroll
        for (int ch = 0; ch < 8; ++ch)
#pragma unroll
            for (int r = 0; r < 16; ++r)
                o[ch][r] *= fsc;

        // bounce P through LDS: write [q][key] (bf16, swizzled)
#pragma unroll
        for (int r = 0; r < 16; ++r) {
            const int km = (r & 3) + 8 * (r >> 2) + 4 * h5;
            const int pb = l31 * 64 + km * 2;
            *(u16*)(Ps + (pb ^ (((l31 >> 1) & 3) << 4))) = f2bf(sv[r]);
        }

        // O^T += V^T * P^T
#pragma unroll
        for (int kk = 0; kk < 2; ++kk) {
            const int pqb = l31 * 64 + kk * 32 + h5 * 16;
            const bf16x8 pf = *(const bf16x8*)(Ps + (pqb ^ (((l31 >> 1) & 3) << 4)));
#pragma unroll
            for (int ch = 0; ch < 8; ++ch) {
                const int d = ch * 32 + l31;
                const int vqb = d * 64 + kk * 32 + h5 * 16;
                const bf16x8 vf = *(const bf16x8*)(Vs + (vqb ^ (((d >> 1) & 3) << 4)));
                o[ch] = __builtin_amdgcn_mfma_f32_32x32x16_bf16(vf, pf, o[ch], 0, 0, 0);
            }
        }
    }

    lrun += __shfl_xor(lrun, 32, 64);
    const float inv = (lrun > 0.0f) ? 1.0f / lrun : 0.0f;

    u16* ab = attnb + (size_t)(b * 2048 + q) * 1024 + h * 256;
#pragma unroll
    for (int ch = 0; ch < 8; ++ch) {
#pragma unroll
        for (int g2 = 0; g2 < 4; ++g2) {
            ushort4 w;
            w.x = f2bf(o[ch][g2 * 4 + 0] * inv);
            w.y = f2bf(o[ch][g2 * 4 + 1] * inv);
            w.z = f2bf(o[ch][g2 * 4 + 2] * inv);
            w.w = f2bf(o[ch][g2 * 4 + 3] * inv);
            *(ushort4*)(ab + ch * 32 + 8 * g2 + 4 * h5) = w;
        }
    }
}

extern "C" void kernel_launch(void* const* d_in, const int* in_sizes, int n_in,
                              void* d_out, int out_size, void* d_ws, size_t ws_size,
                              hipStream_t stream) {
    const float* x   = (const float*)d_in[0];
    const float* Wqk = (const float*)d_in[1];
    const float* bqk = (const float*)d_in[2];
    const float* Wv  = (const float*)d_in[3];
    const float* bv  = (const float*)d_in[4];
    const float* Wo  = (const float*)d_in[5];
    const float* bo  = (const float*)d_in[6];
    float* out = (float*)d_out;

    u16* ws    = (u16*)d_ws;
    u16* xb    = ws;             // 4194304 elems
    u16* wqkb  = ws + 4194304;   // 1048576
    u16* wvb   = ws + 5242880;   // 1048576
    u16* wob   = ws + 6291456;   // 1048576
    u16* qkb   = ws + 7340032;   // 4194304
    u16* vtb   = ws + 11534336;  // 4194304
    u16* attnb = ws + 15728640;  // 4194304   (total ~38 MB)

    cvt_kernel<<<7168, 256, 0, stream>>>(x, Wqk, Wv, Wo, ws);
    gemm_kernel<0><<<512, 256, 0, stream>>>(xb, wqkb, bqk, qkb);
    gemm_kernel<1><<<512, 256, 0, stream>>>(xb, wvb, bv, vtb);
    attn_kernel<<<512, 64, 0, stream>>>(qkb, vtb, attnb);
    gemm_kernel<2><<<512, 256, 0, stream>>>(attnb, wob, bo, out);
}

// Round 2
// 195.546 us; speedup vs baseline: 1.3208x; 1.3208x over previous
//
#include <hip/hip_runtime.h>
#include <cstdint>
#include <cstddef>

typedef unsigned short u16;
typedef __bf16 bf16x8 __attribute__((ext_vector_type(8)));
typedef float f32x4 __attribute__((ext_vector_type(4)));
typedef float f32x16 __attribute__((ext_vector_type(16)));

typedef __attribute__((address_space(1))) void gvoid;
typedef __attribute__((address_space(3))) void lvoid;

__device__ __forceinline__ void g2l16(const void* g, void* l) {
    __builtin_amdgcn_global_load_lds((gvoid*)g, (lvoid*)l, 16, 0, 0);
}

__device__ __forceinline__ u16 f2bf(float f) {
    union { float f; uint32_t u; } v;
    v.f = f;
    uint32_t r = (v.u + 0x7FFFu + ((v.u >> 16) & 1u)) >> 16;
    return (u16)r;
}

// ---------------- fp32 -> bf16 conversion of x, Wqk, Wv, Wo into ws ----------------
__global__ __launch_bounds__(256)
void cvt_kernel(const float* __restrict__ x, const float* __restrict__ wqk,
                const float* __restrict__ wv, const float* __restrict__ wo,
                u16* __restrict__ out) {
    int i = (blockIdx.x * 256 + threadIdx.x) * 4;
    const float* src;
    int off;
    if (i < 4194304)      { src = x;   off = 0; }
    else if (i < 5242880) { src = wqk; off = 4194304; }
    else if (i < 6291456) { src = wv;  off = 5242880; }
    else                  { src = wo;  off = 6291456; }
    float4 v = *(const float4*)(src + (i - off));
    ushort4 o;
    o.x = f2bf(v.x); o.y = f2bf(v.y); o.z = f2bf(v.z); o.w = f2bf(v.w);
    *(ushort4*)(out + i) = o;
}

// ---------------- bf16 GEMM: out[m][n] = sum_k A[m][k]*Bw[n][k] + bias[n] ----------------
// BM=128, BN=128, BK=32, 2-phase double-buffered staging, 256 threads (4 waves 2x2),
// per-wave 64x64 via 16x16x32 mfma. Grid 256 (M/128=32 x N/128=8).
// MODE 0: bf16 out [4096][1024]; MODE 1: bf16 transposed v^T [bh=8][d=256][t=2048]; MODE 2: f32 out.
template <int MODE>
__global__ __launch_bounds__(256)
void gemm_kernel(const u16* __restrict__ A, const u16* __restrict__ Bw,
                 const float* __restrict__ bias, void* __restrict__ outp) {
    __shared__ __align__(16) u16 As[2][128 * 32];
    __shared__ __align__(16) u16 Bs[2][128 * 32];
    const int bid = blockIdx.x;
    const int m0 = (bid >> 3) * 128;
    const int n0 = (bid & 7) * 128;
    const int t = threadIdx.x;
    const int lane = t & 63;
    const int wid = t >> 6;
    const int wr = wid >> 1, wc = wid & 1;
    const int l15 = lane & 15, l4 = lane >> 4;

    f32x4 acc[4][4] = {};

    // stage one BK=32 tile into buffer `buf`
    auto stage = [&](int buf, int kt) {
        const int kbase = kt * 32;
#pragma unroll
        for (int c = 0; c < 2; ++c) {
            const int p = c * 4096 + t * 16;      // byte pos
            const int row = p >> 6;
            const int koff = (p & 63) >> 1;       // elems
            g2l16(A  + (size_t)(m0 + row) * 1024 + kbase + koff, (char*)As[buf] + p);
            g2l16(Bw + (size_t)(n0 + row) * 1024 + kbase + koff, (char*)Bs[buf] + p);
        }
    };

    stage(0, 0);
    asm volatile("s_waitcnt vmcnt(0)" ::: "memory");
    __syncthreads();

    int cur = 0;
    for (int kt = 0; kt < 32; ++kt) {
        if (kt + 1 < 32) stage(cur ^ 1, kt + 1);
        bf16x8 af[4], bfr[4];
#pragma unroll
        for (int mi = 0; mi < 4; ++mi)
            af[mi] = *(const bf16x8*)((const char*)As[cur] + (wr * 64 + mi * 16 + l15) * 64 + l4 * 16);
#pragma unroll
        for (int ni = 0; ni < 4; ++ni)
            bfr[ni] = *(const bf16x8*)((const char*)Bs[cur] + (wc * 64 + ni * 16 + l15) * 64 + l4 * 16);
#pragma unroll
        for (int mi = 0; mi < 4; ++mi)
#pragma unroll
            for (int ni = 0; ni < 4; ++ni)
                acc[mi][ni] = __builtin_amdgcn_mfma_f32_16x16x32_bf16(af[mi], bfr[ni], acc[mi][ni], 0, 0, 0);
        asm volatile("s_waitcnt vmcnt(0)" ::: "memory");
        __syncthreads();
        cur ^= 1;
    }

    const int mbase = m0 + wr * 64 + l4 * 4;
    const int nbase = n0 + wc * 64 + l15;
#pragma unroll
    for (int ni = 0; ni < 4; ++ni) {
        const int n = nbase + ni * 16;
        const float bv = bias[n];
#pragma unroll
        for (int mi = 0; mi < 4; ++mi) {
            const int mrow = mbase + mi * 16;
            if (MODE == 1) {
                const int bq = mrow >> 11, tq = mrow & 2047;
                const int hh = n >> 8, dd = n & 255;
                ushort4 w;
                w.x = f2bf(acc[mi][ni][0] + bv);
                w.y = f2bf(acc[mi][ni][1] + bv);
                w.z = f2bf(acc[mi][ni][2] + bv);
                w.w = f2bf(acc[mi][ni][3] + bv);
                *(ushort4*)((u16*)outp + (size_t)((bq * 4 + hh) * 256 + dd) * 2048 + tq) = w;
            } else if (MODE == 0) {
#pragma unroll
                for (int r = 0; r < 4; ++r)
                    ((u16*)outp)[(size_t)(mrow + r) * 1024 + n] = f2bf(acc[mi][ni][r] + bv);
            } else {
#pragma unroll
                for (int r = 0; r < 4; ++r)
                    ((float*)outp)[(size_t)(mrow + r) * 1024 + n] = acc[mi][ni][r] + bv;
            }
        }
    }
}

// ---------------- spiral flash attention ----------------
// 4 waves/block; block owns (bh, 32-query tile); wave w handles k-tiles w, w+4, ...
// with private (m,l,O); tree-combine at the end. K/V loaded global->reg directly in
// MFMA fragment layout (no LDS in main loop). Swapped operands:
// S^T = mfma(K, Q) so softmax state is lane-local; O^T = mfma(V^T, P^T).
__global__ __launch_bounds__(256, 2)
void attn_kernel(const u16* __restrict__ qk, const u16* __restrict__ vt, u16* __restrict__ attnb) {
    __shared__ float red[32][4][2];
    __shared__ __align__(16) float obuf[2][8192];   // 2 x 32KB tree-combine buffers

    const int bid = blockIdx.x;
    const int bh = bid & 7;                 // bh == XCD -> per-head K/V stays in one L2
    const int qt = 63 - (bid >> 3);
    const int b = bh >> 2, h = bh & 3;
    const int s = (h == 0) ? 1 : ((h == 1) ? 3 : ((h == 2) ? 7 : 13));
    const float rs = 1.0f / (float)s;
    const int t = threadIdx.x;
    const int wid = t >> 6;
    const int l = t & 63;
    const int l31 = l & 31, h5 = l >> 5;
    const int q0 = qt * 32;
    const int q = q0 + l31;                 // this lane's query row
    const float c2 = 0.09016844f;           // (1/16) * log2(e)

    // Q fragments (B-operand of S^T mfma): lane holds Q[q][dc*16 + h5*8 + j]
    bf16x8 qf[16];
    {
        const u16* qb = qk + (size_t)(b * 2048 + q) * 1024 + h * 256 + h5 * 8;
#pragma unroll
        for (int dc = 0; dc < 16; ++dc)
            qf[dc] = *(const bf16x8*)(qb + dc * 16);
    }

    f32x16 o[8] = {};
    float mrun = -3.0e38f, lrun = 0.0f;

    const int nkt = qt + 1;
    for (int kt = wid; kt < nkt; kt += 4) {
        const int key0 = kt * 32;

        // S^T = K * Q^T : K fragments straight from global (16B/lane, L2-hot)
        const u16* kb = qk + (size_t)(b * 2048 + key0 + l31) * 1024 + h * 256 + h5 * 8;
        f32x16 sacc = {};
#pragma unroll
        for (int g = 0; g < 4; ++g) {
            bf16x8 k0 = *(const bf16x8*)(kb + (g * 4 + 0) * 16);
            bf16x8 k1 = *(const bf16x8*)(kb + (g * 4 + 1) * 16);
            bf16x8 k2 = *(const bf16x8*)(kb + (g * 4 + 2) * 16);
            bf16x8 k3 = *(const bf16x8*)(kb + (g * 4 + 3) * 16);
            sacc = __builtin_amdgcn_mfma_f32_32x32x16_bf16(k0, qf[g * 4 + 0], sacc, 0, 0, 0);
            sacc = __builtin_amdgcn_mfma_f32_32x32x16_bf16(k1, qf[g * 4 + 1], sacc, 0, 0, 0);
            sacc = __builtin_amdgcn_mfma_f32_32x32x16_bf16(k2, qf[g * 4 + 2], sacc, 0, 0, 0);
            sacc = __builtin_amdgcn_mfma_f32_32x32x16_bf16(k3, qf[g * 4 + 3], sacc, 0, 0, 0);
        }

        // mask + online softmax (state lane-local for query q)
        const int ebase = (key0 - q + 3072) & 2047;
        float sv[16];
        float tmax = -3.0e38f;
#pragma unroll
        for (int r = 0; r < 16; ++r) {
            const int km = (r & 3) + 8 * (r >> 2) + 4 * h5;   // key row within tile
            int e = ebase + km;
            if (e >= 2048) e -= 2048;
            const int md = e - s * (int)((float)e * rs);
            const bool v = ((key0 + km) <= q) && (md == 0);
            sv[r] = v ? sacc[r] : -3.0e38f;
            tmax = fmaxf(tmax, sv[r]);
        }
        tmax = fmaxf(tmax, __shfl_xor(tmax, 32, 64));
        // defer-max: only rescale when max grew by > 8 (P bounded by 2^(8*c2)=1.65)
        if (!__all(tmax <= mrun + 8.0f)) {
            const float mnew = fmaxf(mrun, tmax);
            const float fsc = __builtin_amdgcn_exp2f((mrun - mnew) * c2);
            lrun *= fsc;
#pragma unroll
            for (int ch = 0; ch < 8; ++ch)
#pragma unroll
                for (int r = 0; r < 16; ++r)
                    o[ch][r] *= fsc;
            mrun = mnew;
        }
        float psum = 0.0f;
#pragma unroll
        for (int r = 0; r < 16; ++r) {
            const float p = (sv[r] > -1.0e37f) ? __builtin_amdgcn_exp2f((sv[r] - mrun) * c2) : 0.0f;
            sv[r] = p;
            psum += p;
        }
        lrun += psum;

        // P -> bf16 fragments in-register: cvt_pk + permlane32_swap (T12)
        uint32_t w0, w1, w2, w3, w4, w5, w6, w7;
        asm("v_cvt_pk_bf16_f32 %0,%1,%2" : "=v"(w0) : "v"(sv[0]),  "v"(sv[1]));
        asm("v_cvt_pk_bf16_f32 %0,%1,%2" : "=v"(w1) : "v"(sv[2]),  "v"(sv[3]));
        asm("v_cvt_pk_bf16_f32 %0,%1,%2" : "=v"(w2) : "v"(sv[4]),  "v"(sv[5]));
        asm("v_cvt_pk_bf16_f32 %0,%1,%2" : "=v"(w3) : "v"(sv[6]),  "v"(sv[7]));
        asm("v_cvt_pk_bf16_f32 %0,%1,%2" : "=v"(w4) : "v"(sv[8]),  "v"(sv[9]));
        asm("v_cvt_pk_bf16_f32 %0,%1,%2" : "=v"(w5) : "v"(sv[10]), "v"(sv[11]));
        asm("v_cvt_pk_bf16_f32 %0,%1,%2" : "=v"(w6) : "v"(sv[12]), "v"(sv[13]));
        asm("v_cvt_pk_bf16_f32 %0,%1,%2" : "=v"(w7) : "v"(sv[14]), "v"(sv[15]));
        asm("v_permlane32_swap_b32 %0, %1" : "+v"(w0), "+v"(w2));
        asm("v_permlane32_swap_b32 %0, %1" : "+v"(w1), "+v"(w3));
        asm("v_permlane32_swap_b32 %0, %1" : "+v"(w4), "+v"(w6));
        asm("v_permlane32_swap_b32 %0, %1" : "+v"(w5), "+v"(w7));
        union { uint32_t u[4]; bf16x8 v; } p0u, p1u;
        p0u.u[0] = w0; p0u.u[1] = w1; p0u.u[2] = w2; p0u.u[3] = w3;
        p1u.u[0] = w4; p1u.u[1] = w5; p1u.u[2] = w6; p1u.u[3] = w7;

        // O^T += V^T * P^T : V fragments straight from global
        const u16* vb = vt + (size_t)(bh * 256 + l31) * 2048 + key0 + h5 * 8;
#pragma unroll
        for (int kk = 0; kk < 2; ++kk) {
            const bf16x8 pf = kk ? p1u.v : p0u.v;
#pragma unroll
            for (int ch = 0; ch < 8; ++ch) {
                const bf16x8 vf = *(const bf16x8*)(vb + (size_t)(ch * 32) * 2048 + kk * 16);
                o[ch] = __builtin_amdgcn_mfma_f32_32x32x16_bf16(vf, pf, o[ch], 0, 0, 0);
            }
        }
    }

    // -------- cross-wave combine --------
    lrun += __shfl_xor(lrun, 32, 64);
    if (h5 == 0) { red[l31][wid][0] = mrun; red[l31][wid][1] = lrun; }
    __syncthreads();
    float M = -3.0e38f;
#pragma unroll
    for (int w = 0; w < 4; ++w) M = fmaxf(M, red[l31][w][0]);
    float L = 0.0f;
#pragma unroll
    for (int w = 0; w < 4; ++w)
        L += red[l31][w][1] * __builtin_amdgcn_exp2f((red[l31][w][0] - M) * c2);
    const float alpha = (L > 0.0f) ? __builtin_amdgcn_exp2f((mrun - M) * c2) / L : 0.0f;
#pragma unroll
    for (int ch = 0; ch < 8; ++ch)
#pragma unroll
        for (int r = 0; r < 16; ++r)
            o[ch][r] *= alpha;

    // tree add: (w0 += w2, w1 += w3) then (w0 += w1); rotated chunks to spread banks
#define OB_ADDR(BUF, C) (obuf[BUF] + l * 128 + ((((C) + l) & 31) << 2))
    if (wid >= 2) {
#pragma unroll
        for (int ch = 0; ch < 8; ++ch)
#pragma unroll
            for (int cc = 0; cc < 4; ++cc) {
                f32x4 v = { o[ch][cc * 4 + 0], o[ch][cc * 4 + 1], o[ch][cc * 4 + 2], o[ch][cc * 4 + 3] };
                *(f32x4*)OB_ADDR(wid - 2, ch * 4 + cc) = v;
            }
    }
    __syncthreads();
    if (wid < 2) {
#pragma unroll
        for (int ch = 0; ch < 8; ++ch)
#pragma unroll
            for (int cc = 0; cc < 4; ++cc) {
                f32x4 v = *(const f32x4*)OB_ADDR(wid, ch * 4 + cc);
#pragma unroll
                for (int j = 0; j < 4; ++j) o[ch][cc * 4 + j] += v[j];
            }
    }
    __syncthreads();
    if (wid == 1) {
#pragma unroll
        for (int ch = 0; ch < 8; ++ch)
#pragma unroll
            for (int cc = 0; cc < 4; ++cc) {
                f32x4 v = { o[ch][cc * 4 + 0], o[ch][cc * 4 + 1], o[ch][cc * 4 + 2], o[ch][cc * 4 + 3] };
                *(f32x4*)OB_ADDR(0, ch * 4 + cc) = v;
            }
    }
    __syncthreads();
    if (wid == 0) {
#pragma unroll
        for (int ch = 0; ch < 8; ++ch)
#pragma unroll
            for (int cc = 0; cc < 4; ++cc) {
                f32x4 v = *(const f32x4*)OB_ADDR(0, ch * 4 + cc);
#pragma unroll
                for (int j = 0; j < 4; ++j) o[ch][cc * 4 + j] += v[j];
            }
        u16* ab = attnb + (size_t)(b * 2048 + q) * 1024 + h * 256;
#pragma unroll
        for (int ch = 0; ch < 8; ++ch) {
#pragma unroll
            for (int g2 = 0; g2 < 4; ++g2) {
                ushort4 w;
                w.x = f2bf(o[ch][g2 * 4 + 0]);
                w.y = f2bf(o[ch][g2 * 4 + 1]);
                w.z = f2bf(o[ch][g2 * 4 + 2]);
                w.w = f2bf(o[ch][g2 * 4 + 3]);
                *(ushort4*)(ab + ch * 32 + 8 * g2 + 4 * h5) = w;
            }
        }
    }
#undef OB_ADDR
}

extern "C" void kernel_launch(void* const* d_in, const int* in_sizes, int n_in,
                              void* d_out, int out_size, void* d_ws, size_t ws_size,
                              hipStream_t stream) {
    const float* x   = (const float*)d_in[0];
    const float* Wqk = (const float*)d_in[1];
    const float* bqk = (const float*)d_in[2];
    const float* Wv  = (const float*)d_in[3];
    const float* bv  = (const float*)d_in[4];
    const float* Wo  = (const float*)d_in[5];
    const float* bo  = (const float*)d_in[6];
    float* out = (float*)d_out;

    u16* ws    = (u16*)d_ws;
    u16* xb    = ws;             // 4194304 elems
    u16* wqkb  = ws + 4194304;   // 1048576
    u16* wvb   = ws + 5242880;   // 1048576
    u16* wob   = ws + 6291456;   // 1048576
    u16* qkb   = ws + 7340032;   // 4194304
    u16* vtb   = ws + 11534336;  // 4194304
    u16* attnb = ws + 15728640;  // 4194304   (total ~38 MB)

    cvt_kernel<<<7168, 256, 0, stream>>>(x, Wqk, Wv, Wo, ws);
    gemm_kernel<0><<<256, 256, 0, stream>>>(xb, wqkb, bqk, qkb);
    gemm_kernel<1><<<256, 256, 0, stream>>>(xb, wvb, bv, vtb);
    attn_kernel<<<512, 256, 0, stream>>>(qkb, vtb, attnb);
    gemm_kernel<2><<<256, 256, 0, stream>>>(attnb, wob, bo, out);
}

// Round 3
// 185.824 us; speedup vs baseline: 1.3899x; 1.0523x over previous
//
#include <hip/hip_runtime.h>
#include <cstdint>
#include <cstddef>

typedef unsigned short u16;
typedef __bf16 bf16x8 __attribute__((ext_vector_type(8)));
typedef float f32x4 __attribute__((ext_vector_type(4)));
typedef float f32x16 __attribute__((ext_vector_type(16)));

typedef __attribute__((address_space(1))) void gvoid;
typedef __attribute__((address_space(3))) void lvoid;

__device__ __forceinline__ void g2l16(const void* g, void* l) {
    __builtin_amdgcn_global_load_lds((gvoid*)g, (lvoid*)l, 16, 0, 0);
}

__device__ __forceinline__ u16 f2bf(float f) {
    union { float f; uint32_t u; } v;
    v.f = f;
    uint32_t r = (v.u + 0x7FFFu + ((v.u >> 16) & 1u)) >> 16;
    return (u16)r;
}

// ---------------- fp32 -> bf16 conversion of x, Wqk, Wv, Wo into ws ----------------
__global__ __launch_bounds__(256)
void cvt_kernel(const float* __restrict__ x, const float* __restrict__ wqk,
                const float* __restrict__ wv, const float* __restrict__ wo,
                u16* __restrict__ out) {
    int i = (blockIdx.x * 256 + threadIdx.x) * 4;
    const float* src;
    int off;
    if (i < 4194304)      { src = x;   off = 0; }
    else if (i < 5242880) { src = wqk; off = 4194304; }
    else if (i < 6291456) { src = wv;  off = 5242880; }
    else                  { src = wo;  off = 6291456; }
    float4 v = *(const float4*)(src + (i - off));
    ushort4 o;
    o.x = f2bf(v.x); o.y = f2bf(v.y); o.z = f2bf(v.z); o.w = f2bf(v.w);
    *(ushort4*)(out + i) = o;
}

// ---------------- bf16 GEMM: out[m][n] = sum_k A[m][k]*Bw[n][k] + bias[n] ----------------
// BM=128, BN=128, BK=32, 2-phase double-buffered staging, 256 threads (4 waves 2x2),
// per-wave 64x64 via 16x16x32 mfma. Grid 256 (M/128=32 x N/128=8).
// MODE 0: bf16 out [4096][1024]; MODE 1: bf16 transposed v^T [bh=8][d=256][t=2048]; MODE 2: f32 out.
template <int MODE>
__global__ __launch_bounds__(256)
void gemm_kernel(const u16* __restrict__ A, const u16* __restrict__ Bw,
                 const float* __restrict__ bias, void* __restrict__ outp) {
    __shared__ __align__(16) u16 As[2][128 * 32];
    __shared__ __align__(16) u16 Bs[2][128 * 32];
    const int bid = blockIdx.x;
    const int m0 = (bid >> 3) * 128;
    const int n0 = (bid & 7) * 128;
    const int t = threadIdx.x;
    const int lane = t & 63;
    const int wid = t >> 6;
    const int wr = wid >> 1, wc = wid & 1;
    const int l15 = lane & 15, l4 = lane >> 4;

    f32x4 acc[4][4] = {};

    auto stage = [&](int buf, int kt) {
        const int kbase = kt * 32;
#pragma unroll
        for (int c = 0; c < 2; ++c) {
            const int p = c * 4096 + t * 16;      // byte pos
            const int row = p >> 6;
            const int koff = (p & 63) >> 1;       // elems
            g2l16(A  + (size_t)(m0 + row) * 1024 + kbase + koff, (char*)As[buf] + p);
            g2l16(Bw + (size_t)(n0 + row) * 1024 + kbase + koff, (char*)Bs[buf] + p);
        }
    };

    stage(0, 0);
    asm volatile("s_waitcnt vmcnt(0)" ::: "memory");
    __syncthreads();

    int cur = 0;
    for (int kt = 0; kt < 32; ++kt) {
        if (kt + 1 < 32) stage(cur ^ 1, kt + 1);
        bf16x8 af[4], bfr[4];
#pragma unroll
        for (int mi = 0; mi < 4; ++mi)
            af[mi] = *(const bf16x8*)((const char*)As[cur] + (wr * 64 + mi * 16 + l15) * 64 + l4 * 16);
#pragma unroll
        for (int ni = 0; ni < 4; ++ni)
            bfr[ni] = *(const bf16x8*)((const char*)Bs[cur] + (wc * 64 + ni * 16 + l15) * 64 + l4 * 16);
#pragma unroll
        for (int mi = 0; mi < 4; ++mi)
#pragma unroll
            for (int ni = 0; ni < 4; ++ni)
                acc[mi][ni] = __builtin_amdgcn_mfma_f32_16x16x32_bf16(af[mi], bfr[ni], acc[mi][ni], 0, 0, 0);
        asm volatile("s_waitcnt vmcnt(0)" ::: "memory");
        __syncthreads();
        cur ^= 1;
    }

    const int mbase = m0 + wr * 64 + l4 * 4;
    const int nbase = n0 + wc * 64 + l15;
#pragma unroll
    for (int ni = 0; ni < 4; ++ni) {
        const int n = nbase + ni * 16;
        const float bv = bias[n];
#pragma unroll
        for (int mi = 0; mi < 4; ++mi) {
            const int mrow = mbase + mi * 16;
            if (MODE == 1) {
                const int bq = mrow >> 11, tq = mrow & 2047;
                const int hh = n >> 8, dd = n & 255;
                ushort4 w;
                w.x = f2bf(acc[mi][ni][0] + bv);
                w.y = f2bf(acc[mi][ni][1] + bv);
                w.z = f2bf(acc[mi][ni][2] + bv);
                w.w = f2bf(acc[mi][ni][3] + bv);
                *(ushort4*)((u16*)outp + (size_t)((bq * 4 + hh) * 256 + dd) * 2048 + tq) = w;
            } else if (MODE == 0) {
#pragma unroll
                for (int r = 0; r < 4; ++r)
                    ((u16*)outp)[(size_t)(mrow + r) * 1024 + n] = f2bf(acc[mi][ni][r] + bv);
            } else {
#pragma unroll
                for (int r = 0; r < 4; ++r)
                    ((float*)outp)[(size_t)(mrow + r) * 1024 + n] = acc[mi][ni][r] + bv;
            }
        }
    }
}

// ---------------- spiral flash attention (LDS-staged) ----------------
// Block = 4 waves, QBLK=64 (wave qs in {0,1} owns 32 queries), staged 64-key supertile
// (K [64][256] 32KB + V^T [256][64] 32KB), double-buffered = 128KB LDS.
// Wave (qs,kh) computes its q-subtile vs key-half kh of each staged tile (k-split 2,
// private m/l/O, 2-way combine at end through dead staging LDS).
// Swapped operands: S^T = mfma(K,Q) -> softmax lane-local; O^T = mfma(V^T, P^T).
__global__ __launch_bounds__(256)
void attn_kernel(const u16* __restrict__ qk, const u16* __restrict__ vt, u16* __restrict__ attnb) {
    __shared__ __align__(16) unsigned char sm[133120];
    // [0,65536)   : buf0  (K 32KB | V 32KB)
    // [65536,131072): buf1
    // [131072,...) : red[2][32][2][2] floats
    float* red = (float*)(sm + 131072);

    const int bid = blockIdx.x;
    const int bh = bid & 7;                  // one head per XCD -> K/V L2-resident
    const int c = 31 - (bid >> 3);           // 64-query column, biggest first
    const int b = bh >> 2, h = bh & 3;
    const int s = (h == 0) ? 1 : ((h == 1) ? 3 : ((h == 2) ? 7 : 13));
    const float rs = 1.0f / (float)s;
    const int t = threadIdx.x;
    const int wid = t >> 6;
    const int qs = wid >> 1, kh = wid & 1;
    const int l = t & 63;
    const int l31 = l & 31, h5 = l >> 5;
    const int q = c * 64 + qs * 32 + l31;    // this lane's query row
    const float c2 = 0.09016844f;            // (1/16) * log2(e)

    // Q fragments (B-operand of S^T mfma): lane holds Q[q][dc*16 + h5*8 + j]  (one-time scatter)
    bf16x8 qf[16];
    {
        const u16* qb = qk + (size_t)(b * 2048 + q) * 1024 + h * 256 + h5 * 8;
#pragma unroll
        for (int dc = 0; dc < 16; ++dc)
            qf[dc] = *(const bf16x8*)(qb + dc * 16);
    }

    const int nG = c + 1;

    // stage 64-key group g into buffer `buf` (coalesced global, pre-swizzled source)
    auto stage = [&](int g, int buf) {
        const size_t kgbase = (size_t)(b * 2048 + g * 64) * 1024 + h * 256;
        unsigned char* Kd = sm + buf * 65536;
        unsigned char* Vd = Kd + 32768;
#pragma unroll
        for (int i = 0; i < 8; ++i) {
            const int p = i * 4096 + t * 16;
            const int q1 = p ^ (((p >> 9) & 31) << 4);   // K rows are 512B
            g2l16(qk + kgbase + (size_t)(q1 >> 9) * 1024 + ((q1 & 511) >> 1), Kd + p);
        }
#pragma unroll
        for (int i = 0; i < 8; ++i) {
            const int p = i * 4096 + t * 16;
            const int q2 = p ^ (((p >> 7) & 7) << 4);    // V^T rows are 128B
            g2l16(vt + (size_t)(bh * 256 + (q2 >> 7)) * 2048 + g * 64 + ((q2 & 127) >> 1), Vd + p);
        }
    };

    f32x16 o[8] = {};
    float mrun = -3.0e38f, lrun = 0.0f;

    stage(0, 0);
    asm volatile("s_waitcnt vmcnt(0)" ::: "memory");
    __syncthreads();

    int buf = 0;
    for (int g = 0; g < nG; ++g) {
        if (g + 1 < nG) stage(g + 1, buf ^ 1);

        const unsigned char* Kb = sm + buf * 65536;
        const unsigned char* Vb = Kb + 32768;
        const int key0 = g * 64 + kh * 32;

        // S^T = K * Q^T
        f32x16 sacc = {};
#pragma unroll
        for (int dc = 0; dc < 16; ++dc) {
            const int ba = (kh * 32 + l31) * 512 + dc * 32 + h5 * 16;
            const bf16x8 kf = *(const bf16x8*)(Kb + (ba ^ (((ba >> 9) & 31) << 4)));
            sacc = __builtin_amdgcn_mfma_f32_32x32x16_bf16(kf, qf[dc], sacc, 0, 0, 0);
        }

        // mask + online softmax (state lane-local for query q)
        const int ebase = (key0 - q + 3072) & 2047;
        float sv[16];
        float tmax = -3.0e38f;
#pragma unroll
        for (int r = 0; r < 16; ++r) {
            const int km = (r & 3) + 8 * (r >> 2) + 4 * h5;   // key row within 32-key tile
            int e = ebase + km;
            if (e >= 2048) e -= 2048;
            const int md = e - s * (int)((float)e * rs);
            const bool v = ((key0 + km) <= q) && (md == 0);
            sv[r] = v ? sacc[r] : -3.0e38f;
            tmax = fmaxf(tmax, sv[r]);
        }
        tmax = fmaxf(tmax, __shfl_xor(tmax, 32, 64));
        // defer-max: only rescale when max grew by > 8
        if (!__all(tmax <= mrun + 8.0f)) {
            const float mnew = fmaxf(mrun, tmax);
            const float fsc = __builtin_amdgcn_exp2f((mrun - mnew) * c2);
            lrun *= fsc;
#pragma unroll
            for (int ch = 0; ch < 8; ++ch)
#pragma unroll
                for (int r = 0; r < 16; ++r)
                    o[ch][r] *= fsc;
            mrun = mnew;
        }
        float psum = 0.0f;
#pragma unroll
        for (int r = 0; r < 16; ++r) {
            const float p = (sv[r] > -1.0e37f) ? __builtin_amdgcn_exp2f((sv[r] - mrun) * c2) : 0.0f;
            sv[r] = p;
            psum += p;
        }
        lrun += psum;

        // P -> bf16 fragments in-register: cvt_pk + permlane32_swap (T12)
        uint32_t w0, w1, w2, w3, w4, w5, w6, w7;
        asm("v_cvt_pk_bf16_f32 %0,%1,%2" : "=v"(w0) : "v"(sv[0]),  "v"(sv[1]));
        asm("v_cvt_pk_bf16_f32 %0,%1,%2" : "=v"(w1) : "v"(sv[2]),  "v"(sv[3]));
        asm("v_cvt_pk_bf16_f32 %0,%1,%2" : "=v"(w2) : "v"(sv[4]),  "v"(sv[5]));
        asm("v_cvt_pk_bf16_f32 %0,%1,%2" : "=v"(w3) : "v"(sv[6]),  "v"(sv[7]));
        asm("v_cvt_pk_bf16_f32 %0,%1,%2" : "=v"(w4) : "v"(sv[8]),  "v"(sv[9]));
        asm("v_cvt_pk_bf16_f32 %0,%1,%2" : "=v"(w5) : "v"(sv[10]), "v"(sv[11]));
        asm("v_cvt_pk_bf16_f32 %0,%1,%2" : "=v"(w6) : "v"(sv[12]), "v"(sv[13]));
        asm("v_cvt_pk_bf16_f32 %0,%1,%2" : "=v"(w7) : "v"(sv[14]), "v"(sv[15]));
        asm("v_permlane32_swap_b32 %0, %1" : "+v"(w0), "+v"(w2));
        asm("v_permlane32_swap_b32 %0, %1" : "+v"(w1), "+v"(w3));
        asm("v_permlane32_swap_b32 %0, %1" : "+v"(w4), "+v"(w6));
        asm("v_permlane32_swap_b32 %0, %1" : "+v"(w5), "+v"(w7));
        union { uint32_t u[4]; bf16x8 v; } p0u, p1u;
        p0u.u[0] = w0; p0u.u[1] = w1; p0u.u[2] = w2; p0u.u[3] = w3;
        p1u.u[0] = w4; p1u.u[1] = w5; p1u.u[2] = w6; p1u.u[3] = w7;

        // O^T += V^T * P^T
#pragma unroll
        for (int kk = 0; kk < 2; ++kk) {
            const bf16x8 pf = kk ? p1u.v : p0u.v;
#pragma unroll
            for (int ch = 0; ch < 8; ++ch) {
                const int aa = (ch * 32 + l31) * 128 + kh * 64 + kk * 32 + h5 * 16;
                const bf16x8 vf = *(const bf16x8*)(Vb + (aa ^ (((aa >> 7) & 7) << 4)));
                o[ch] = __builtin_amdgcn_mfma_f32_32x32x16_bf16(vf, pf, o[ch], 0, 0, 0);
            }
        }

        asm volatile("s_waitcnt vmcnt(0)" ::: "memory");
        __syncthreads();
        buf ^= 1;
    }

    // -------- 2-way combine over kh (per q-subtile), reusing staging LDS --------
    lrun += __shfl_xor(lrun, 32, 64);
    if (h5 == 0) {
        red[((qs * 32 + l31) * 2 + kh) * 2 + 0] = mrun;
        red[((qs * 32 + l31) * 2 + kh) * 2 + 1] = lrun;
    }
    __syncthreads();
    const float m0 = red[((qs * 32 + l31) * 2 + 0) * 2 + 0];
    const float l0 = red[((qs * 32 + l31) * 2 + 0) * 2 + 1];
    const float m1 = red[((qs * 32 + l31) * 2 + 1) * 2 + 0];
    const float l1 = red[((qs * 32 + l31) * 2 + 1) * 2 + 1];
    const float M = fmaxf(m0, m1);
    const float L = l0 * __builtin_amdgcn_exp2f((m0 - M) * c2)
                  + l1 * __builtin_amdgcn_exp2f((m1 - M) * c2);
    const float alpha = (L > 0.0f) ? __builtin_amdgcn_exp2f((mrun - M) * c2) / L : 0.0f;
#pragma unroll
    for (int ch = 0; ch < 8; ++ch)
#pragma unroll
        for (int r = 0; r < 16; ++r)
            o[ch][r] *= alpha;

    // kh=1 writes scaled O into region qs (32KB); kh=0 adds and writes out
    float* ob = (float*)(sm + qs * 32768);
#define OB_ADDR(C) (ob + l * 128 + ((((C) + l) & 31) << 2))
    if (kh == 1) {
#pragma unroll
        for (int ch = 0; ch < 8; ++ch)
#pragma unroll
            for (int cc = 0; cc < 4; ++cc) {
                f32x4 v = { o[ch][cc * 4 + 0], o[ch][cc * 4 + 1], o[ch][cc * 4 + 2], o[ch][cc * 4 + 3] };
                *(f32x4*)OB_ADDR(ch * 4 + cc) = v;
            }
    }
    __syncthreads();
    if (kh == 0) {
#pragma unroll
        for (int ch = 0; ch < 8; ++ch)
#pragma unroll
            for (int cc = 0; cc < 4; ++cc) {
                f32x4 v = *(const f32x4*)OB_ADDR(ch * 4 + cc);
#pragma unroll
                for (int j = 0; j < 4; ++j) o[ch][cc * 4 + j] += v[j];
            }
        u16* ab = attnb + (size_t)(b * 2048 + q) * 1024 + h * 256;
#pragma unroll
        for (int ch = 0; ch < 8; ++ch) {
#pragma unroll
            for (int g2 = 0; g2 < 4; ++g2) {
                ushort4 w;
                w.x = f2bf(o[ch][g2 * 4 + 0]);
                w.y = f2bf(o[ch][g2 * 4 + 1]);
                w.z = f2bf(o[ch][g2 * 4 + 2]);
                w.w = f2bf(o[ch][g2 * 4 + 3]);
                *(ushort4*)(ab + ch * 32 + 8 * g2 + 4 * h5) = w;
            }
        }
    }
#undef OB_ADDR
}

extern "C" void kernel_launch(void* const* d_in, const int* in_sizes, int n_in,
                              void* d_out, int out_size, void* d_ws, size_t ws_size,
                              hipStream_t stream) {
    const float* x   = (const float*)d_in[0];
    const float* Wqk = (const float*)d_in[1];
    const float* bqk = (const float*)d_in[2];
    const float* Wv  = (const float*)d_in[3];
    const float* bv  = (const float*)d_in[4];
    const float* Wo  = (const float*)d_in[5];
    const float* bo  = (const float*)d_in[6];
    float* out = (float*)d_out;

    u16* ws    = (u16*)d_ws;
    u16* xb    = ws;             // 4194304 elems
    u16* wqkb  = ws + 4194304;   // 1048576
    u16* wvb   = ws + 5242880;   // 1048576
    u16* wob   = ws + 6291456;   // 1048576
    u16* qkb   = ws + 7340032;   // 4194304
    u16* vtb   = ws + 11534336;  // 4194304
    u16* attnb = ws + 15728640;  // 4194304   (total ~38 MB)

    cvt_kernel<<<7168, 256, 0, stream>>>(x, Wqk, Wv, Wo, ws);
    gemm_kernel<0><<<256, 256, 0, stream>>>(xb, wqkb, bqk, qkb);
    gemm_kernel<1><<<256, 256, 0, stream>>>(xb, wvb, bv, vtb);
    attn_kernel<<<256, 256, 0, stream>>>(qkb, vtb, attnb);
    gemm_kernel<2><<<256, 256, 0, stream>>>(attnb, wob, bo, out);
}